// Round 10
// baseline (857.767 us; speedup 1.0000x reference)
//
#include <hip/hip_runtime.h>

#define TTL 98
#define OUTD 10

typedef float f16v __attribute__((ext_vector_type(16)));
typedef short short8 __attribute__((ext_vector_type(8)));
typedef unsigned short ushort;

constexpr size_t MM = 1048576;
constexpr size_t OFF_OSUM = 5 * MM;                  // 10,240
constexpr size_t OFF_XT   = OFF_OSUM + 10240;        // 802,816 (tables reuse after kL1)
constexpr size_t OFF_S1B  = OFF_XT + 802816;         // u32: 98*512*32
constexpr size_t OFF_S1BT = OFF_S1B + 1605632;       // u32: 98*16*1024
constexpr size_t OFF_S2BF = OFF_S1BT + 1605632;      // u32: 98*1024*32 (full-row L2 bits)
constexpr size_t OFF_S2BT = OFF_S2BF + 3211264;      // u32: 98*32*1024 (bit-transposed)
constexpr size_t OFF_W2S  = OFF_S2BT + 3211264;      // bf16 3*2*1024*512
constexpr size_t OFF_W3S  = OFF_W2S + 1572864;       // bf16 3*1024*1024 (full rows)
constexpr size_t FIX_END  = OFF_W3S + 1572864;       // 18,835,456 floats (75.3 MB)

constexpr size_t TAB_IDX2 = 0;        // 98*384
constexpr size_t TAB_IDX3 = 37632;    // 98*320
constexpr size_t TAB_RK2  = 68992;    // 98*1024
constexpr size_t TAB_RK3  = 169344;   // 98*1024

// ---- exact 3-way bf16 split by truncation: hi+mid+lo == w bit-exactly ----
__device__ inline void split3(float w, ushort& h, ushort& m, ushort& l) {
    unsigned u = __float_as_uint(w);
    h = (ushort)(u >> 16);
    float r1 = w - __uint_as_float(u & 0xFFFF0000u);
    unsigned u1 = __float_as_uint(r1);
    m = (ushort)(u1 >> 16);
    float r2 = r1 - __uint_as_float(u1 & 0xFFFF0000u);
    l = (ushort)(__float_as_uint(r2) >> 16);
}

// ---- 8 spike bits (low byte of x) -> short8 of bf16 {0,1} via multiply-spread + perm ----
__device__ inline short8 expand8(unsigned x) {
    unsigned lo = ((x & 0xFu) * 0x00204081u) & 0x01010101u;
    unsigned hi = (((x >> 4) & 0xFu) * 0x00204081u) & 0x01010101u;
    lo *= 0xFFu; hi *= 0xFFu;            // byte masks: bit e -> byte e = 0xFF/0x00
    union { unsigned u[4]; short8 v; } r;
    r.u[0] = __builtin_amdgcn_perm(lo, lo, 0x01010000u) & 0x3F803F80u;
    r.u[1] = __builtin_amdgcn_perm(lo, lo, 0x03030202u) & 0x3F803F80u;
    r.u[2] = __builtin_amdgcn_perm(hi, hi, 0x01010000u) & 0x3F803F80u;
    r.u[3] = __builtin_amdgcn_perm(hi, hi, 0x03030202u) & 0x3F803F80u;
    return r.v;
}

// ---- split weights: W2S[pi][p][i][q] (j=2q+p), W3S[pi][i][j] (full rows) ----
__global__ __launch_bounds__(256) void kSplit(
    const float* __restrict__ W2, const float* __restrict__ W3,
    ushort* __restrict__ W2S, ushort* __restrict__ W3S)
{
    int id = blockIdx.x * 256 + threadIdx.x;
    if (id < 1048576) {
        int p = id >> 19, rem = id & 524287, i = rem >> 9, q = rem & 511;
        ushort h, m, l;
        split3(W2[i * 1024 + 2 * q + p], h, m, l);
        size_t base = (size_t)p * 524288 + (size_t)i * 512 + q;
        W2S[base] = h; W2S[base + 1048576] = m; W2S[base + 2097152] = l;
    } else {
        int e = id - 1048576;
        ushort h, m, l;
        split3(W3[e], h, m, l);
        W3S[e] = h; W3S[e + 1048576] = m; W3S[e + 2097152] = l;
    }
}

// ---- transpose input -> xT[784][1024] ----
__global__ __launch_bounds__(256) void kPrep(const float* __restrict__ input,
                                             float* __restrict__ xT)
{
    __shared__ float Ls[64][65];
    int bx = blockIdx.x, tid = threadIdx.x;
    int wt = bx >> 4, nt = bx & 15;
    int w0 = wt * 64, n0 = nt * 64;
#pragma unroll
    for (int j = 0; j < 16; ++j) {
        int flat = tid + 256 * j;
        int a = flat >> 6, c = flat & 63;
        Ls[a][c] = (w0 + c < 784) ? input[(size_t)(n0 + a) * 784 + w0 + c] : 0.f;
    }
    __syncthreads();
#pragma unroll
    for (int j = 0; j < 16; ++j) {
        int flat = tid + 256 * j;
        int ii = flat >> 6, nn = flat & 63;
        if (w0 + ii < 784) xT[(size_t)(w0 + ii) * 1024 + n0 + nn] = Ls[nn][ii];
    }
}

// ---- layer-1 full trajectory (4 rows/wave, x prefetch) -> spike bits + counts ----
__global__ __launch_bounds__(256) void kL1(
    const float* __restrict__ xT, const float* __restrict__ W1,
    const float* __restrict__ b1,
    unsigned long long* __restrict__ s1bits, float* __restrict__ ss1)
{
    int tid = threadIdx.x;
    int waveId = (blockIdx.x << 2) + (tid >> 6);   // 0..4095
    int lane = tid & 63;
    int rowg = waveId >> 4;                        // 0..255
    int nblk = waveId & 15;
    int i0 = rowg << 2;
    int n = (nblk << 6) + lane;
    float w[4][8], bb[4], mem[4], cnt[4];
#pragma unroll
    for (int r = 0; r < 4; ++r) {
#pragma unroll
        for (int e = 0; e < 8; ++e) w[r][e] = W1[(i0 + r) * 8 + e];
        bb[r] = b1[i0 + r]; mem[r] = 0.f; cnt[r] = 0.f;
    }
    float x[8], xn[8];
#pragma unroll
    for (int e = 0; e < 8; ++e) x[e] = xT[(size_t)e * 1024 + n];
    for (int t = 0; t < TTL; ++t) {
        if (t + 1 < TTL) {
            int st1 = ((t + 1) * 8 < TTL - 8) ? (t + 1) * 8 : (784 - 8);
#pragma unroll
            for (int e = 0; e < 8; ++e) xn[e] = xT[(size_t)(st1 + e) * 1024 + n];
        }
#pragma unroll
        for (int r = 0; r < 4; ++r) {
            if (((t ^ (i0 + r)) & 1) == 0) {       // parity rule exact for cycle 2 (98 even)
                float d = bb[r];
#pragma unroll
                for (int e = 0; e < 8; ++e) d += w[r][e] * x[e];
                float m = mem[r] * 0.5f + d;       // prev spike provably 0 at active steps
                mem[r] = m;
                bool sp = m > 0.5f;
                unsigned long long bm = __ballot(sp);
                if (lane == 0) s1bits[(size_t)(t * 512 + ((i0 + r) >> 1)) * 16 + nblk] = bm;
                if (sp) cnt[r] += 1.f;
            }
        }
#pragma unroll
        for (int e = 0; e < 8; ++e) x[e] = xn[e];
    }
#pragma unroll
    for (int r = 0; r < 4; ++r) ss1[(size_t)(i0 + r) * 1024 + n] = cnt[r];
}

// ---- per-t tables via prefix scan: u=(t-i) mod 98 (98%3,4 != 0 -> table, not residue) ----
__global__ __launch_bounds__(256) void kTab2(
    int* __restrict__ idx2, int* __restrict__ idx3,
    int* __restrict__ rank2, int* __restrict__ rank3)
{
    __shared__ int f2[256], f3[256];
    __shared__ int sidx2[384], sidx3[320];
    int t = blockIdx.x, tid = threadIdx.x;
    int a2[4], a3[4];
    int l2 = 0, l3 = 0;
#pragma unroll
    for (int e = 0; e < 4; ++e) {
        int i = tid * 4 + e;
        int u = (t - i) % TTL; if (u < 0) u += TTL;
        a2[e] = (u % 3 == 0); a3[e] = (u % 4 == 0);
        l2 += a2[e]; l3 += a3[e];
    }
    f2[tid] = l2; f3[tid] = l3;
    __syncthreads();
    for (int s = 1; s < 256; s <<= 1) {
        int v2 = (tid >= s) ? f2[tid - s] : 0;
        int v3 = (tid >= s) ? f3[tid - s] : 0;
        __syncthreads();
        f2[tid] += v2; f3[tid] += v3;
        __syncthreads();
    }
    int o2 = f2[tid] - l2, o3 = f3[tid] - l3;
    int c2 = f2[255], c3 = f3[255];
#pragma unroll
    for (int e = 0; e < 4; ++e) {
        int i = tid * 4 + e;
        if (a2[e]) { rank2[t * 1024 + i] = o2; sidx2[o2] = i; ++o2; }
        else rank2[t * 1024 + i] = -1;
        if (a3[e]) { rank3[t * 1024 + i] = o3; sidx3[o3] = i; ++o3; }
        else rank3[t * 1024 + i] = -1;
    }
    __syncthreads();
    for (int k = tid; k < 384; k += 256) idx2[t * 384 + k] = (k < c2) ? sidx2[k] : -1;
    for (int k = tid; k < 320; k += 256) idx3[t * 320 + k] = (k < c3) ? sidx3[k] : -1;
}

// ---- bit-matrix transpose: [t][k][n-words] -> [t][k-words][n], t0-offset ----
template<int K>
__global__ __launch_bounds__(256) void kXb(const unsigned* __restrict__ in,
                                           unsigned* __restrict__ out, int t0)
{
    constexpr int Kw = K / 32;
    __shared__ unsigned L[1024];
    int bx = blockIdx.x, tid = threadIdx.x;
    int tt = t0 + bx / Kw, kw = bx % Kw;
    const unsigned* ip = in + ((size_t)tt * K + kw * 32) * 32;
#pragma unroll
    for (int g = 0; g < 4; ++g) L[g * 256 + tid] = ip[g * 256 + tid];
    __syncthreads();
    unsigned* op = out + ((size_t)tt * Kw + kw) * 1024;
#pragma unroll
    for (int g = 0; g < 4; ++g) {
        int n = g * 256 + tid;
        int w = n >> 5, b = n & 31;
        unsigned acc = 0;
#pragma unroll
        for (int k = 0; k < 32; ++k) acc |= ((L[k * 32 + w] >> b) & 1u) << k;
        op[n] = acc;
    }
}

// ==================== barrier-free, LDS-free GEMMs ====================
// A fragments loaded per-lane directly from global (16B contiguous); B = register bit-expand.

// layer-2: rows via idx2, cols parity-compact K=512; grid nt*24
__global__ __launch_bounds__(256) void kGM2K(
    const ushort* __restrict__ Ws, const unsigned* __restrict__ s1bT,
    const int* __restrict__ idx2, float* __restrict__ drive, int t0)
{
    int tid = threadIdx.x, bx = blockIdx.x;
    int tloc = bx / 24, rem = bx % 24;
    int mt = rem >> 2, nt4 = rem & 3;
    int t = t0 + tloc;
    int r0 = mt * 64, n0 = nt4 * 256;
    int wv = tid >> 6, lane = tid & 63;
    int wr = (wv >> 1) * 32, wc = (wv & 1) * 128;
    int mrow = lane & 31, kh8 = (lane >> 5) * 8;
    int vr = idx2[t * 384 + r0 + wr + mrow];
    const ushort* Wb = Ws + (size_t)(t & 1) * 524288 +
                       (size_t)(vr < 0 ? 0 : vr) * 512 + kh8;
    const unsigned* Bp = s1bT + (size_t)t * 16384 + n0 + wc + mrow;
    f16v acc[4];
#pragma unroll
    for (int j = 0; j < 4; ++j) acc[j] = (f16v)(0.f);

    for (int kc = 0; kc < 512; kc += 32) {
        unsigned w4[4];
#pragma unroll
        for (int j = 0; j < 4; ++j) w4[j] = Bp[(kc >> 5) * 1024 + j * 32];
        const ushort* wp = Wb + kc;
        short8 af[3][2];
#pragma unroll
        for (int pi = 0; pi < 3; ++pi) {
            af[pi][0] = *(const short8*)(wp + (size_t)pi * 1048576);
            af[pi][1] = *(const short8*)(wp + (size_t)pi * 1048576 + 16);
        }
#pragma unroll
        for (int s2 = 0; s2 < 2; ++s2) {
            int kcol = s2 * 16 + kh8;
            short8 bf[4];
#pragma unroll
            for (int j = 0; j < 4; ++j) bf[j] = expand8(w4[j] >> kcol);
#pragma unroll
            for (int pi = 2; pi >= 0; --pi)
#pragma unroll
                for (int j = 0; j < 4; ++j)
                    acc[j] = __builtin_amdgcn_mfma_f32_32x32x16_bf16(af[pi][s2], bf[j], acc[j], 0, 0, 0);
        }
    }
#pragma unroll
    for (int j = 0; j < 4; ++j)
#pragma unroll
        for (int reg = 0; reg < 16; ++reg) {
            int rowl = wr + (reg & 3) + 8 * (reg >> 2) + 4 * (lane >> 5);
            drive[((size_t)tloc * 384 + r0 + rowl) * 1024 + n0 + wc + j * 32 + mrow] = acc[j][reg];
        }
}

// layer-3: rows via idx3, full K=1024 (inactive B rows are zero bits); grid nt*20
__global__ __launch_bounds__(256) void kGM3K(
    const ushort* __restrict__ Ws, const unsigned* __restrict__ s2bT,
    const int* __restrict__ idx3, float* __restrict__ drive, int t0)
{
    int tid = threadIdx.x, bx = blockIdx.x;
    int tloc = bx / 20, rem = bx % 20;
    int mt = rem >> 2, nt4 = rem & 3;
    int t = t0 + tloc;
    int r0 = mt * 64, n0 = nt4 * 256;
    int wv = tid >> 6, lane = tid & 63;
    int wr = (wv >> 1) * 32, wc = (wv & 1) * 128;
    int mrow = lane & 31, kh8 = (lane >> 5) * 8;
    int vr = idx3[t * 320 + r0 + wr + mrow];
    const ushort* Wb = Ws + (size_t)(vr < 0 ? 0 : vr) * 1024 + kh8;
    const unsigned* Bp = s2bT + (size_t)t * 32768 + n0 + wc + mrow;
    f16v acc[4];
#pragma unroll
    for (int j = 0; j < 4; ++j) acc[j] = (f16v)(0.f);

    for (int kc = 0; kc < 1024; kc += 32) {
        unsigned w4[4];
#pragma unroll
        for (int j = 0; j < 4; ++j) w4[j] = Bp[(kc >> 5) * 1024 + j * 32];
        const ushort* wp = Wb + kc;
        short8 af[3][2];
#pragma unroll
        for (int pi = 0; pi < 3; ++pi) {
            af[pi][0] = *(const short8*)(wp + (size_t)pi * 1048576);
            af[pi][1] = *(const short8*)(wp + (size_t)pi * 1048576 + 16);
        }
#pragma unroll
        for (int s2 = 0; s2 < 2; ++s2) {
            int kcol = s2 * 16 + kh8;
            short8 bf[4];
#pragma unroll
            for (int j = 0; j < 4; ++j) bf[j] = expand8(w4[j] >> kcol);
#pragma unroll
            for (int pi = 2; pi >= 0; --pi)
#pragma unroll
                for (int j = 0; j < 4; ++j)
                    acc[j] = __builtin_amdgcn_mfma_f32_32x32x16_bf16(af[pi][s2], bf[j], acc[j], 0, 0, 0);
        }
    }
#pragma unroll
    for (int j = 0; j < 4; ++j)
#pragma unroll
        for (int reg = 0; reg < 16; ++reg) {
            int rowl = wr + (reg & 3) + 8 * (reg >> 2) + 4 * (lane >> 5);
            drive[((size_t)tloc * 320 + r0 + rowl) * 1024 + n0 + wc + j * 32 + mrow] = acc[j][reg];
        }
}

// ---- chunk recurrence (4 rows/wave); BITS: write full-row bit matrix incl. zeros ----
template<int MP, bool BITS>
__global__ __launch_bounds__(256) void kRK(
    const float* __restrict__ drive, const float* __restrict__ bias,
    const int* __restrict__ rank,
    float* __restrict__ mG, float* __restrict__ ssG,
    unsigned long long* __restrict__ bitsOut, int t0, int nt)
{
    int tid = threadIdx.x;
    int waveId = (blockIdx.x << 2) + (tid >> 6);
    int lane = tid & 63;
    int rowg = waveId >> 4, nblk = waveId & 15;
    int i0 = rowg << 2;
    int n = (nblk << 6) + lane;
    float mv[4], cnt[4], bv[4];
#pragma unroll
    for (int r = 0; r < 4; ++r) {
        mv[r] = mG[(size_t)(i0 + r) * 1024 + n];
        cnt[r] = 0.f;
        bv[r] = bias[i0 + r];
    }
    for (int tl = 0; tl < nt; ++tl) {
        int t = t0 + tl;
#pragma unroll
        for (int r = 0; r < 4; ++r) {
            int i = i0 + r;
            int rk = rank[t * 1024 + i];
            if (rk >= 0) {
                float d = drive[((size_t)tl * MP + rk) * 1024 + n] + bv[r];
                float m = mv[r] * 0.5f + d;
                mv[r] = m;
                bool sp = m > 0.5f;
                if (BITS) {
                    unsigned long long bm = __ballot(sp);
                    if (lane == 0) bitsOut[((size_t)t * 1024 + i) * 16 + nblk] = bm;
                }
                if (sp) cnt[r] += 1.f;
            } else if (BITS) {
                if (lane == 0) bitsOut[((size_t)t * 1024 + i) * 16 + nblk] = 0ULL;
            }
        }
    }
#pragma unroll
    for (int r = 0; r < 4; ++r) {
        size_t idx = (size_t)(i0 + r) * 1024 + n;
        mG[idx] = mv[r];
        ssG[idx] += cnt[r];
    }
}

// ---- tail: ss transposes + fr; W4 GEMV partials into osum ----
__global__ __launch_bounds__(256) void kTail(
    const float* __restrict__ ssBase, const float* __restrict__ W4,
    float* __restrict__ osum, float* __restrict__ out, float* __restrict__ fr)
{
    int bx = blockIdx.x, tid = threadIdx.x;
    if (bx < 768) {
        __shared__ float Ls[64][65];
        __shared__ float red[4];
        int l = bx >> 8;
        int tile = bx & 255;
        int i0 = (tile >> 4) * 64, n0 = (tile & 15) * 64;
        const float* ss = ssBase + (size_t)l * MM;
        float* o = out + 10240 + (size_t)l * MM;
        float sum = 0.f;
#pragma unroll
        for (int j = 0; j < 16; ++j) {
            int flat = tid + 256 * j;
            int a = flat >> 6, c = flat & 63;
            float v = ss[(size_t)(i0 + a) * 1024 + n0 + c];
            Ls[a][c] = v;
            sum += v;
        }
        __syncthreads();
        for (int off = 32; off > 0; off >>= 1) sum += __shfl_down(sum, off, 64);
        if ((tid & 63) == 0) red[tid >> 6] = sum;
        __syncthreads();
        if (tid == 0) {
            float s = red[0] + red[1] + red[2] + red[3];
            atomicAdd(&fr[l], s * (1.0f / (1024.0f * 1024.0f * 98.0f)));
        }
#pragma unroll
        for (int j = 0; j < 16; ++j) {
            int flat = tid + 256 * j;
            int nn = flat >> 6, ii = flat & 63;
            o[(size_t)(n0 + nn) * 1024 + i0 + ii] = Ls[ii][nn] * (1.0f / 98.0f);
        }
    } else {
        int b = bx - 768;
        int ks = b >> 4, nt = b & 15;
        int n = nt * 64 + (tid & 63);
        int og = tid >> 6;
        const float* ss3 = ssBase + (size_t)2 * MM;
        float a0 = 0.f, a1 = 0.f, a2 = 0.f;
        int k0 = ks * 256;
        for (int k = k0; k < k0 + 256; ++k) {
            float v = ss3[(size_t)k * 1024 + n];
            a0 += v * W4[og * 1024 + k];
            a1 += v * W4[(og + 4) * 1024 + k];
            if (og < 2) a2 += v * W4[(og + 8) * 1024 + k];
        }
        atomicAdd(&osum[n * OUTD + og], a0);
        atomicAdd(&osum[n * OUTD + og + 4], a1);
        if (og < 2) atomicAdd(&osum[n * OUTD + og + 8], a2);
    }
}

__global__ void kOut(const float* __restrict__ osum, const float* __restrict__ b4,
                     float* __restrict__ out)
{
    int idx = blockIdx.x * 256 + threadIdx.x;
    if (idx < 1024 * OUTD) out[idx] = osum[idx] * (1.0f / 98.0f) + b4[idx % OUTD];
}

extern "C" void kernel_launch(void* const* d_in, const int* in_sizes, int n_in,
                              void* d_out, int out_size, void* d_ws, size_t ws_size,
                              hipStream_t stream)
{
    const float* input = (const float*)d_in[0];
    const float* W1    = (const float*)d_in[1];
    const float* b1    = (const float*)d_in[2];
    const float* W2    = (const float*)d_in[3];
    const float* b2    = (const float*)d_in[4];
    const float* W3    = (const float*)d_in[5];
    const float* b3    = (const float*)d_in[6];
    const float* W4    = (const float*)d_in[7];
    const float* b4    = (const float*)d_in[8];

    float* ws = (float*)d_ws;
    float* ss1  = ws;
    float* ss2  = ws + MM;
    float* ss3  = ws + 2 * MM;
    float* m2   = ws + 3 * MM;
    float* m3   = ws + 4 * MM;
    float* osum = ws + OFF_OSUM;
    float* xT   = ws + OFF_XT;
    int*   tabs = (int*)(ws + OFF_XT);   // reuses xT region after kL1
    int* idx2  = tabs + TAB_IDX2;
    int* idx3  = tabs + TAB_IDX3;
    int* rank2 = tabs + TAB_RK2;
    int* rank3 = tabs + TAB_RK3;
    unsigned int* s1b  = (unsigned int*)(ws + OFF_S1B);
    unsigned int* s1bT = (unsigned int*)(ws + OFF_S1BT);
    unsigned int* s2bF = (unsigned int*)(ws + OFF_S2BF);
    unsigned int* s2bT = (unsigned int*)(ws + OFF_S2BT);
    ushort* W2S = (ushort*)(ws + OFF_W2S);
    ushort* W3S = (ushort*)(ws + OFF_W3S);
    float* out  = (float*)d_out;

    // pick the largest t-chunk the workspace can hold (drive buffers: tc*704*1024 floats)
    size_t availF = ws_size / sizeof(float);
    int tc = 14;
    const int cands[5] = {98, 49, 33, 25, 14};
    for (int ci = 0; ci < 5; ++ci) {
        if (FIX_END + (size_t)cands[ci] * 704 * 1024 <= availF) { tc = cands[ci]; break; }
    }
    float* drv2 = ws + FIX_END;
    float* drv3 = drv2 + (size_t)tc * 384 * 1024;

    hipMemsetAsync(ws, 0, (5 * MM + 10240) * sizeof(float), stream);   // ss, m2, m3, osum
    hipMemsetAsync(out + 3155968, 0, 3 * sizeof(float), stream);       // fr

    kSplit<<<8192, 256, 0, stream>>>(W2, W3, W2S, W3S);
    kPrep<<<208, 256, 0, stream>>>(input, xT);
    kL1<<<1024, 256, 0, stream>>>(xT, W1, b1, (unsigned long long*)s1b, ss1);
    kTab2<<<98, 256, 0, stream>>>(idx2, idx3, rank2, rank3);           // after kL1: reuses xT mem
    kXb<512><<<1568, 256, 0, stream>>>(s1b, s1bT, 0);

    for (int t0 = 0; t0 < TTL; t0 += tc) {
        int nt = (TTL - t0 < tc) ? (TTL - t0) : tc;
        kGM2K<<<nt * 24, 256, 0, stream>>>(W2S, s1bT, idx2, drv2, t0);
        kRK<384, true><<<1024, 256, 0, stream>>>(drv2, b2, rank2, m2, ss2,
                                                 (unsigned long long*)s2bF, t0, nt);
        kXb<1024><<<nt * 32, 256, 0, stream>>>(s2bF, s2bT, t0);
        kGM3K<<<nt * 20, 256, 0, stream>>>(W3S, s2bT, idx3, drv3, t0);
        kRK<320, false><<<1024, 256, 0, stream>>>(drv3, b3, rank3, m3, ss3,
                                                  nullptr, t0, nt);
    }

    kTail<<<832, 256, 0, stream>>>(ss1, W4, osum, out, out + 3155968);
    kOut<<<40, 256, 0, stream>>>(osum, b4, out);
}